// Round 1
// baseline (207.273 us; speedup 1.0000x reference)
//
#include <hip/hip_runtime.h>
#include <hip/hip_bf16.h>

namespace {

constexpr int HEADS = 4;
constexpr int DQ    = 128;
constexpr int NMAX  = 512;   // max_len from timestamps shape (N+1 = 513)
constexpr int QB    = 128;   // q rows per block (32 per wave)
constexpr int KVB   = 64;    // kv rows per tile
constexpr int ROWF  = 3 * DQ * HEADS;  // 1536 floats per token row
constexpr float ALPHA = 0.08838834764831843f;
constexpr float INV_N = 1.0f / 512.0f;

typedef __bf16 bf16x8 __attribute__((ext_vector_type(8)));
typedef float  f32x16 __attribute__((ext_vector_type(16)));

__device__ __forceinline__ unsigned short f2bf(float f) {
  union { float f; unsigned u; } v; v.f = f;
  unsigned r = v.u + 0x7FFFu + ((v.u >> 16) & 1u);
  return (unsigned short)(r >> 16);
}

// swizzle for transposed-V LDS rows (128B): spreads both read lanes (d consecutive)
// and write lanes (d = 2*lane) across 16B bank-slots
__device__ __forceinline__ int vswz(int d) {
  return ((d & 7) ^ ((d >> 2) & 7)) << 4;
}

__device__ __forceinline__ f32x16 zero16() {
  f32x16 z;
#pragma unroll
  for (int i = 0; i < 16; i++) z[i] = 0.0f;
  return z;
}

} // namespace

__global__ __launch_bounds__(256)
void hstu_attn_kernel(const float* __restrict__ qkv,
                      const int* __restrict__ seq_offsets,
                      float* __restrict__ out)
{
  const int qt  = blockIdx.x;
  const int b   = blockIdx.y;
  const int h   = blockIdx.z;
  const int off = seq_offsets[b];
  const int len = seq_offsets[b + 1] - off;
  const int n0  = qt * QB;
  if (n0 >= len) return;

  // K tile [m][d] (bf16, swizzled), V tile transposed [d][m], P per-wave [n][m]
  __shared__ __align__(16) unsigned short Ks[KVB * DQ];     // 16 KB
  __shared__ __align__(16) unsigned short Vts[DQ * KVB];    // 16 KB
  __shared__ __align__(16) unsigned short Ps[4][32 * KVB];  // 16 KB

  const int t   = threadIdx.x;
  const int w   = t >> 6;     // wave id 0..3
  const int l   = t & 63;     // lane
  const int l31 = l & 31;
  const int g   = l >> 5;     // half-wave group
  const int nb  = n0 + 32 * w;  // this wave's first q row

  // ---- Q fragments: 32 rows/wave, 8 K-slices of 16 (A-frag: row=l&31, k=g*8+j) ----
  bf16x8 qf[8];
  {
    int n  = nb + l31;
    int rq = n < len ? n : len - 1;   // clamp: rows >= len are never stored
    const float* qrow = qkv + (size_t)(off + rq) * ROWF + h * (3 * DQ);
#pragma unroll
    for (int ks = 0; ks < 8; ks++) {
      int d = ks * 16 + g * 8;
      float4 a0 = *(const float4*)(qrow + d);
      float4 a1 = *(const float4*)(qrow + d + 4);
      bf16x8 f;
      f[0] = (__bf16)a0.x; f[1] = (__bf16)a0.y; f[2] = (__bf16)a0.z; f[3] = (__bf16)a0.w;
      f[4] = (__bf16)a1.x; f[5] = (__bf16)a1.y; f[6] = (__bf16)a1.z; f[7] = (__bf16)a1.w;
      qf[ks] = f;
    }
  }

  f32x16 Of[4];
#pragma unroll
  for (int i = 0; i < 4; i++) Of[i] = zero16();

  const int nkv_len = (len + KVB - 1) >> 6;
  const int nkv     = min(nkv_len, 2 * qt + 2);

  for (int kvt = 0; kvt < nkv; kvt++) {
    const int m0 = kvt * KVB;

    // ---- stage K: row-major [m][d], swizzle ((m&7)<<4) ----
#pragma unroll
    for (int j = 0; j < 8; j++) {
      int idx = t + j * 256;          // 0..2047 over 64 rows x 32 float4
      int r   = idx >> 5;
      int d   = (idx & 31) * 4;
      int m   = m0 + r;
      int rm  = m < len ? m : len - 1;
      float4 k4 = *(const float4*)(qkv + (size_t)(off + rm) * ROWF + h * (3 * DQ) + DQ + d);
      ushort4 pk;
      pk.x = f2bf(k4.x); pk.y = f2bf(k4.y); pk.z = f2bf(k4.z); pk.w = f2bf(k4.w);
      *(ushort4*)((char*)Ks + r * 256 + ((d * 2) ^ ((r & 7) << 4))) = pk;
    }

    // ---- stage V transposed: Vts[d][m], pack 4 m-values per write ----
    {
      int d0 = (t & 63) * 2;
      int mg = (t >> 6) * 4;
#pragma unroll
      for (int p = 0; p < 4; p++) {
        int mr = p * 16 + mg;
        float2 vv[4];
#pragma unroll
        for (int j = 0; j < 4; j++) {
          int m  = m0 + mr + j;
          int rm = m < len ? m : len - 1;
          vv[j] = *(const float2*)(qkv + (size_t)(off + rm) * ROWF + h * (3 * DQ) + 2 * DQ + d0);
        }
        ushort4 w0, w1;
        w0.x = f2bf(vv[0].x); w0.y = f2bf(vv[1].x); w0.z = f2bf(vv[2].x); w0.w = f2bf(vv[3].x);
        w1.x = f2bf(vv[0].y); w1.y = f2bf(vv[1].y); w1.z = f2bf(vv[2].y); w1.w = f2bf(vv[3].y);
        *(ushort4*)((char*)Vts + d0 * 128 + ((2 * mr) ^ vswz(d0)))       = w0;
        *(ushort4*)((char*)Vts + (d0 + 1) * 128 + ((2 * mr) ^ vswz(d0 + 1))) = w1;
      }
    }
    __syncthreads();

    if (m0 <= nb + 31) {   // wave-uniform: skip tiles entirely above the diagonal
      const bool needmask = (m0 + KVB - 1) > nb;

      // ---- QK^T: S tile 32n x 64m (two 32x32 frags) ----
      f32x16 Sf[2];
#pragma unroll
      for (int mt = 0; mt < 2; mt++) {
        f32x16 acc = zero16();
        int mrow = mt * 32 + l31;
#pragma unroll
        for (int ks = 0; ks < 8; ks++) {
          int cb = (ks * 16 + g * 8) * 2;
          bf16x8 kb = *(const bf16x8*)((char*)Ks + mrow * 256 + (cb ^ ((mrow & 7) << 4)));
          acc = __builtin_amdgcn_mfma_f32_32x32x16_bf16(qf[ks], kb, acc, 0, 0, 0);
        }
        Sf[mt] = acc;
      }

      // ---- silu + causal mask -> P (bf16) in per-wave LDS [n][m] ----
#pragma unroll
      for (int mt = 0; mt < 2; mt++) {
        int mloc = mt * 32 + l31;
#pragma unroll
        for (int r = 0; r < 16; r++) {
          int nloc = 4 * g + (r & 3) + 8 * (r >> 2);
          float s = Sf[mt][r] * ALPHA;
          float p = s * __builtin_amdgcn_rcpf(1.0f + __expf(-s)) * INV_N;
          if (needmask && (m0 + mloc) > (nb + nloc)) p = 0.0f;
          *(unsigned short*)((char*)(Ps[w]) + nloc * 128 + ((2 * mloc) ^ ((nloc & 7) << 4))) = f2bf(p);
        }
      }

      // ---- PV: O += P * V  (A = P from LDS, B = V^T from LDS) ----
#pragma unroll
      for (int sk = 0; sk < 4; sk++) {
        int cb = (sk * 16 + g * 8) * 2;
        bf16x8 pa = *(const bf16x8*)((char*)(Ps[w]) + l31 * 128 + (cb ^ ((l31 & 7) << 4)));
#pragma unroll
        for (int dt = 0; dt < 4; dt++) {
          int d = dt * 32 + l31;
          bf16x8 vb = *(const bf16x8*)((char*)Vts + d * 128 + (cb ^ vswz(d)));
          Of[dt] = __builtin_amdgcn_mfma_f32_32x32x16_bf16(pa, vb, Of[dt], 0, 0, 0);
        }
      }
    }
    __syncthreads();
  }

  // ---- epilogue: write O rows n < len ----
#pragma unroll
  for (int dt = 0; dt < 4; dt++) {
    int d = dt * 32 + l31;
#pragma unroll
    for (int r = 0; r < 16; r++) {
      int nloc = 4 * g + (r & 3) + 8 * (r >> 2);
      int n = nb + nloc;
      if (n < len)
        out[(size_t)(off + n) * (HEADS * DQ) + h * DQ + d] = Of[dt][r];
    }
  }
}

extern "C" void kernel_launch(void* const* d_in, const int* in_sizes, int n_in,
                              void* d_out, int out_size, void* d_ws, size_t ws_size,
                              hipStream_t stream) {
  const float* qkv         = (const float*)d_in[0];
  const int*   seq_offsets = (const int*)d_in[1];
  float*       out         = (float*)d_out;
  int Zq = in_sizes[1] - 1;  // number of sequences (offsets has Z+1 entries)
  dim3 grid((NMAX + QB - 1) / QB, Zq, HEADS);
  hstu_attn_kernel<<<grid, dim3(256), 0, stream>>>(qkv, seq_offsets, out);
}

// Round 2
// 152.673 us; speedup vs baseline: 1.3576x; 1.3576x over previous
//
#include <hip/hip_runtime.h>
#include <hip/hip_bf16.h>

namespace {

constexpr int HEADS = 4;
constexpr int DQ    = 128;
constexpr int QB    = 128;   // q rows per block (32 per wave)
constexpr int KVB   = 64;    // kv rows per tile
constexpr int ROWF  = 3 * DQ * HEADS;  // 1536 floats per token row
constexpr float ALPHA = 0.08838834764831843f;
constexpr float INV_N = 1.0f / 512.0f;

typedef __bf16 bf16x8 __attribute__((ext_vector_type(8)));
typedef float  f32x16 __attribute__((ext_vector_type(16)));
typedef float  f32x4  __attribute__((ext_vector_type(4)));
typedef unsigned int u32;
typedef u32 u32x4 __attribute__((ext_vector_type(4)));

union FragU { u32x4 u; bf16x8 v; };

__device__ __forceinline__ u32 pkbf(float lo, float hi) {
  u32 r;
  asm("v_cvt_pk_bf16_f32 %0, %1, %2" : "=v"(r) : "v"(lo), "v"(hi));
  return r;
}

__device__ __forceinline__ u32 xor32(u32 x) {
  return (u32)__shfl_xor((int)x, 32, 64);
}

// swizzle for transposed-V LDS rows (128B)
__device__ __forceinline__ int vswz(int d) {
  return ((d & 7) ^ ((d >> 2) & 7)) << 4;
}

__device__ __forceinline__ float silu_p(float acc) {
  float s = acc * ALPHA;
  return s * INV_N * __builtin_amdgcn_rcpf(1.0f + __expf(-s));
}

} // namespace

__global__ __launch_bounds__(256)
void hstu_attn_kernel(const float* __restrict__ qkv,
                      const int* __restrict__ seq_offsets,
                      float* __restrict__ out)
{
  const int qt  = blockIdx.x;
  const int b   = blockIdx.y;
  const int h   = blockIdx.z;
  const int off = seq_offsets[b];
  const int len = seq_offsets[b + 1] - off;
  const int n0  = qt * QB;
  if (n0 >= len) return;

  __shared__ __align__(16) unsigned short Ks[KVB * DQ];   // 16 KB, swizzled rows
  __shared__ __align__(16) unsigned short Vts[DQ * KVB];  // 16 KB, transposed+swizzled

  const int t   = threadIdx.x;
  const int l   = t & 63;
  const int l31 = l & 31;
  const int g   = l >> 5;
  const int nb  = n0 + 32 * (t >> 6);   // wave's first q row

  const float* base = qkv + h * (3 * DQ);

  // staging geometry: K -> thread owns (row kr, d kd0..kd0+31); V -> (8 rows vm0.., 4 cols vd0..)
  const int kr  = t >> 2;
  const int kd0 = (t & 3) * 32;
  const int vm0 = (t & 7) * 8;
  const int vd0 = (t >> 3) * 4;

  f32x4 kraw[8];
  f32x4 vraw[8];

  auto issue_loads = [&](int m0) {
    int rm = m0 + kr; rm = rm < len ? rm : len - 1;
    const f32x4* kp = (const f32x4*)(base + (size_t)(off + rm) * ROWF + DQ + kd0);
#pragma unroll
    for (int i = 0; i < 8; i++) kraw[i] = kp[i];
#pragma unroll
    for (int j = 0; j < 8; j++) {
      int m = m0 + vm0 + j; int rv = m < len ? m : len - 1;
      vraw[j] = *(const f32x4*)(base + (size_t)(off + rv) * ROWF + 2 * DQ + vd0);
    }
  };

  auto pack_write = [&]() {
    char* kb = (char*)Ks + kr * 256;
    const int ksw = (kr & 7) << 4;
#pragma unroll
    for (int i = 0; i < 4; i++) {
      u32x4 wv;
      wv[0] = pkbf(kraw[2 * i][0], kraw[2 * i][1]);
      wv[1] = pkbf(kraw[2 * i][2], kraw[2 * i][3]);
      wv[2] = pkbf(kraw[2 * i + 1][0], kraw[2 * i + 1][1]);
      wv[3] = pkbf(kraw[2 * i + 1][2], kraw[2 * i + 1][3]);
      *(u32x4*)(kb + ((2 * (kd0 + 8 * i)) ^ ksw)) = wv;
    }
#pragma unroll
    for (int dd = 0; dd < 4; dd++) {
      int d = vd0 + dd;
      u32x4 wv;
      wv[0] = pkbf(vraw[0][dd], vraw[1][dd]);
      wv[1] = pkbf(vraw[2][dd], vraw[3][dd]);
      wv[2] = pkbf(vraw[4][dd], vraw[5][dd]);
      wv[3] = pkbf(vraw[6][dd], vraw[7][dd]);
      *(u32x4*)((char*)Vts + d * 128 + ((2 * vm0) ^ vswz(d))) = wv;
    }
  };

  issue_loads(0);   // prefetch tile 0 while we set up Q

  // Q fragments (B-operand of swapped QK^T): lane holds Q[n=l31][d = 16ks + 8g + j]
  bf16x8 qf[8];
  {
    int n  = nb + l31;
    int rq = n < len ? n : len - 1;   // clamped rows never written
    const float* qrow = base + (size_t)(off + rq) * ROWF;
#pragma unroll
    for (int ks = 0; ks < 8; ks++) {
      int d = ks * 16 + g * 8;
      f32x4 a0 = *(const f32x4*)(qrow + d);
      f32x4 a1 = *(const f32x4*)(qrow + d + 4);
      FragU u;
      u.u[0] = pkbf(a0[0], a0[1]);
      u.u[1] = pkbf(a0[2], a0[3]);
      u.u[2] = pkbf(a1[0], a1[1]);
      u.u[3] = pkbf(a1[2], a1[3]);
      qf[ks] = u.v;
    }
  }

  f32x16 Of[4];
#pragma unroll
  for (int i = 0; i < 4; i++)
#pragma unroll
    for (int r = 0; r < 16; r++) Of[i][r] = 0.0f;

  const int nkv = min((len + KVB - 1) >> 6, 2 * qt + 2);

  for (int kvt = 0; kvt < nkv; kvt++) {
    const int m0 = kvt * KVB;
    __syncthreads();                       // all waves done reading previous tile
    pack_write();                          // f32->bf16, write LDS (waits raw loads)
    if (kvt + 1 < nkv) issue_loads(m0 + KVB);  // async prefetch under compute
    __syncthreads();

    if (m0 <= nb + 31) {                   // wave-uniform diagonal skip
      const bool needmask = (m0 + KVB - 1) > nb;
      bf16x8 pa[4];

#pragma unroll
      for (int mt = 0; mt < 2; mt++) {
        f32x16 acc;
#pragma unroll
        for (int r = 0; r < 16; r++) acc[r] = 0.0f;
        const int mrow = mt * 32 + l31;
        const char* krow = (const char*)Ks + mrow * 256;
        const int sw = (mrow & 7) << 4;
        __builtin_amdgcn_s_setprio(1);
#pragma unroll
        for (int ks = 0; ks < 8; ks++) {
          int cb = (ks * 16 + g * 8) * 2;
          bf16x8 kb = *(const bf16x8*)(krow + (cb ^ sw));
          // S^T = K * Q^T : D[row=m][col=n], lane holds n=l31, m=(r&3)+8(r>>2)+4g+32mt
          acc = __builtin_amdgcn_mfma_f32_32x32x16_bf16(kb, qf[ks], acc, 0, 0, 0);
        }
        __builtin_amdgcn_s_setprio(0);

        // silu + causal mask, pack to bf16 pairs (m, m+1)
        u32 w[8];
#pragma unroll
        for (int i = 0; i < 8; i++) {
          int r  = 2 * i;
          int mr = m0 + (r & 3) + 8 * (r >> 2) + 4 * g + 32 * mt;
          float p0 = silu_p(acc[r]);
          float p1 = silu_p(acc[r + 1]);
          if (needmask) {
            int nglob = nb + l31;
            if (mr > nglob)     p0 = 0.0f;
            if (mr + 1 > nglob) p1 = 0.0f;
          }
          w[i] = pkbf(p0, p1);
        }

        // redistribute halves lane<->lane+32: build PV A-frags (k = 8g + j)
        FragU fa, fb;
        {
          u32 t0 = xor32(w[0]);
          u32 t2 = xor32(w[2]);
          fa.u[0] = g ? t2 : w[0];
          fa.u[2] = g ? w[2] : t0;
          u32 t1 = xor32(w[1]);
          u32 t3 = xor32(w[3]);
          fa.u[1] = g ? t3 : w[1];
          fa.u[3] = g ? w[3] : t1;
          u32 t4 = xor32(w[4]);
          u32 t6 = xor32(w[6]);
          fb.u[0] = g ? t6 : w[4];
          fb.u[2] = g ? w[6] : t4;
          u32 t5 = xor32(w[5]);
          u32 t7 = xor32(w[7]);
          fb.u[1] = g ? t7 : w[5];
          fb.u[3] = g ? w[7] : t5;
        }
        pa[2 * mt]     = fa.v;
        pa[2 * mt + 1] = fb.v;
      }

      // PV: O += P * V^T  (A = P frags in reg, B = V^T from LDS)
      __builtin_amdgcn_s_setprio(1);
#pragma unroll
      for (int ks = 0; ks < 4; ks++) {
        int cb = (ks * 16 + g * 8) * 2;
#pragma unroll
        for (int dt = 0; dt < 4; dt++) {
          int d = dt * 32 + l31;
          bf16x8 vb = *(const bf16x8*)((char*)Vts + d * 128 + (cb ^ vswz(d)));
          Of[dt] = __builtin_amdgcn_mfma_f32_32x32x16_bf16(pa[ks], vb, Of[dt], 0, 0, 0);
        }
      }
      __builtin_amdgcn_s_setprio(0);
    }
  }

  // epilogue: write O rows n < len (coalesced 4B stores, d = dt*32 + l31)
#pragma unroll
  for (int dt = 0; dt < 4; dt++) {
    int d = dt * 32 + l31;
#pragma unroll
    for (int r = 0; r < 16; r++) {
      int nloc = 4 * g + (r & 3) + 8 * (r >> 2);
      int n = nb + nloc;
      if (n < len)
        out[(size_t)(off + n) * (HEADS * DQ) + h * DQ + d] = Of[dt][r];
    }
  }
}

extern "C" void kernel_launch(void* const* d_in, const int* in_sizes, int n_in,
                              void* d_out, int out_size, void* d_ws, size_t ws_size,
                              hipStream_t stream) {
  const float* qkv         = (const float*)d_in[0];
  const int*   seq_offsets = (const int*)d_in[1];
  float*       out         = (float*)d_out;
  int Zq = in_sizes[1] - 1;
  // max len = 383 (256 + z%256, z<128) -> 3 q-tiles of 128 suffice
  dim3 grid(3, Zq, HEADS);
  hstu_attn_kernel<<<grid, dim3(256), 0, stream>>>(qkv, seq_offsets, out);
}

// Round 3
// 118.352 us; speedup vs baseline: 1.7513x; 1.2900x over previous
//
#include <hip/hip_runtime.h>
#include <hip/hip_bf16.h>

namespace {

constexpr int HEADS = 4;
constexpr int DQ    = 128;
constexpr int KVB   = 64;
constexpr int ROWF  = 3 * DQ * HEADS;  // 1536 floats per token row
constexpr int WAVES = 12;              // 12 waves x 32 q-rows = 384 >= max len 383
constexpr int THREADS = 64 * WAVES;
constexpr float ALPHA = 0.08838834764831843f;
constexpr float INV_N = 1.0f / 512.0f;

typedef __bf16 bf16x8 __attribute__((ext_vector_type(8)));
typedef float  f32x16 __attribute__((ext_vector_type(16)));
typedef float  f32x4  __attribute__((ext_vector_type(4)));
typedef unsigned int u32;
typedef u32 u32x4 __attribute__((ext_vector_type(4)));

union FragU { u32x4 u; bf16x8 v; };

__device__ __forceinline__ u32 pkbf(float lo, float hi) {
  u32 r;
  asm("v_cvt_pk_bf16_f32 %0, %1, %2" : "=v"(r) : "v"(lo), "v"(hi));
  return r;
}

__device__ __forceinline__ u32 xor32(u32 x) {
  return (u32)__shfl_xor((int)x, 32, 64);
}

__device__ __forceinline__ float silu_p(float acc) {
  float s = acc * ALPHA;
  return s * INV_N * __builtin_amdgcn_rcpf(1.0f + __expf(-s));
}

#define GLOAD16(gp, lp) \
  __builtin_amdgcn_global_load_lds((const __attribute__((address_space(1))) u32*)(gp), \
                                   (__attribute__((address_space(3))) u32*)(lp), 16, 0, 0)

} // namespace

// One block per (b, h). 12 waves, wave w owns q-rows 32w..32w+31.
// K/V tiles (KVB=64 rows) staged once: global f32 -> LDS f32 (async DMA,
// source pre-swizzled) -> cvt pass -> LDS bf16 (K row-major, V transposed).
__global__ __launch_bounds__(THREADS, 3)
void hstu_attn_kernel(const float* __restrict__ qkv,
                      const int* __restrict__ seq_offsets,
                      float* __restrict__ out)
{
  const int b   = (int)gridDim.x - 1 - (int)blockIdx.x;  // longest-first
  const int h   = blockIdx.y;
  const int off = seq_offsets[b];
  const int len = seq_offsets[b + 1] - off;

  __shared__ __align__(16) float          Kf[KVB * DQ];   // 32 KB raw f32, swizzled(&31)
  __shared__ __align__(16) float          Vf[KVB * DQ];   // 32 KB raw f32, swizzled(&31)
  __shared__ __align__(16) unsigned short Kb[KVB * DQ];   // 16 KB bf16 [m][d], swizzled(&15)
  __shared__ __align__(16) unsigned short Vtb[KVB * DQ];  // 16 KB bf16 V^T: row=d>>1 (256B), swizzled(&15)

  const int t   = threadIdx.x;
  const int w   = t >> 6;
  const int l   = t & 63;
  const int l31 = l & 31;
  const int g   = l >> 5;
  const int nb  = 32 * w;   // wave's first q row (sequence-local)

  const float* __restrict__ base = qkv + (size_t)off * ROWF + h * (3 * DQ);

  // ---- async stage tile (f32 K and V) via global_load_lds, pre-swizzled source ----
  auto issue_stage = [&](int m0) {
    const int p    = l & 31;       // physical 16B slot within 512B row-half
    const int rsub = l >> 5;
#pragma unroll
    for (int i = w; i < 32; i += WAVES) {       // K: 32 x 1KB calls
      int r  = 2 * i + rsub;
      int rm = m0 + r; rm = rm < len ? rm : len - 1;
      int c  = p ^ (r & 31);                    // logical chunk for this physical slot
      GLOAD16(base + (size_t)rm * ROWF + DQ + c * 4, (char*)Kf + i * 1024);
    }
#pragma unroll
    for (int i = w; i < 32; i += WAVES) {       // V: 32 x 1KB calls
      int r  = 2 * i + rsub;
      int rm = m0 + r; rm = rm < len ? rm : len - 1;
      int c  = p ^ (r & 31);
      GLOAD16(base + (size_t)rm * ROWF + 2 * DQ + c * 4, (char*)Vf + i * 1024);
    }
  };

  // ---- cvt pass: LDS f32 -> LDS bf16 (K row-major, V transposed) ----
  auto cvt_pass = [&]() {
    if (t < 256) {
      // V: thread owns rows m0p, m0p+1 and d-range d0..d0+15
      const int m0p = (t >> 3) * 2;
      const int d0  = (t & 7) * 16;
      f32x4 r0[4], r1[4];
#pragma unroll
      for (int i = 0; i < 4; i++) {
        int c = (t & 7) * 4 + i;
        r0[i] = *(const f32x4*)((char*)Vf + m0p * 512 + ((c ^ (m0p & 31)) << 4));
        r1[i] = *(const f32x4*)((char*)Vf + (m0p + 1) * 512 + ((c ^ ((m0p + 1) & 31)) << 4));
      }
#pragma unroll
      for (int j = 0; j < 16; j++) {
        int d   = d0 + j;
        int row = d >> 1;
        int ch  = (d & 1) * 8 + (m0p >> 3);
        *(u32*)((char*)Vtb + row * 256 + ((ch ^ (row & 15)) << 4) + (m0p & 7) * 2)
            = pkbf(r0[j >> 2][j & 3], r1[j >> 2][j & 3]);
      }
    } else {
      // K: thread owns row m, d-range (t2&7)*16..+15
      const int t2 = t - 256;
      const int m  = t2 >> 3;
      f32x4 r[4];
#pragma unroll
      for (int i = 0; i < 4; i++) {
        int c = (t2 & 7) * 4 + i;
        r[i] = *(const f32x4*)((char*)Kf + m * 512 + ((c ^ (m & 31)) << 4));
      }
      u32x4 w0, w1;
      w0[0] = pkbf(r[0][0], r[0][1]); w0[1] = pkbf(r[0][2], r[0][3]);
      w0[2] = pkbf(r[1][0], r[1][1]); w0[3] = pkbf(r[1][2], r[1][3]);
      w1[0] = pkbf(r[2][0], r[2][1]); w1[1] = pkbf(r[2][2], r[2][3]);
      w1[2] = pkbf(r[3][0], r[3][1]); w1[3] = pkbf(r[3][2], r[3][3]);
      const int cb = (t2 & 7) * 2;
      *(u32x4*)((char*)Kb + m * 256 + ((cb ^ (m & 15)) << 4))       = w0;
      *(u32x4*)((char*)Kb + m * 256 + (((cb + 1) ^ (m & 15)) << 4)) = w1;
    }
  };

  issue_stage(0);   // DMA tile 0 while we build Q fragments

  // ---- Q fragments (B-operand of swapped QK^T): lane holds Q[n=l31][d=16ks+8g+j] ----
  bf16x8 qf[8];
  {
    int n  = nb + l31;
    int rq = n < len ? n : len - 1;   // clamped rows never stored
    const float* qrow = base + (size_t)rq * ROWF;
#pragma unroll
    for (int ks = 0; ks < 8; ks++) {
      int d = ks * 16 + g * 8;
      f32x4 a0 = *(const f32x4*)(qrow + d);
      f32x4 a1 = *(const f32x4*)(qrow + d + 4);
      FragU u;
      u.u[0] = pkbf(a0[0], a0[1]);
      u.u[1] = pkbf(a0[2], a0[3]);
      u.u[2] = pkbf(a1[0], a1[1]);
      u.u[3] = pkbf(a1[2], a1[3]);
      qf[ks] = u.v;
    }
  }

  f32x16 Of[4];
#pragma unroll
  for (int i = 0; i < 4; i++)
#pragma unroll
    for (int r = 0; r < 16; r++) Of[i][r] = 0.0f;

  const int nkv = (len + KVB - 1) >> 6;

  for (int kvt = 0; kvt < nkv; kvt++) {
    const int m0 = kvt * KVB;
    asm volatile("s_waitcnt vmcnt(0)" ::: "memory");  // DMA for tile kvt landed
    __syncthreads();                                  // + all waves done with prev bf16
    cvt_pass();
    __syncthreads();                                  // bf16 ready; f32 buffers free
    if (kvt + 1 < nkv) issue_stage(m0 + KVB);         // DMA next tile under compute

    if (nb < len && m0 <= nb + 31) {                  // wave-uniform causal skip
      const bool needmask = (m0 + KVB - 1) > nb;
      bf16x8 pa[4];

#pragma unroll
      for (int mt = 0; mt < 2; mt++) {
        f32x16 acc;
#pragma unroll
        for (int r = 0; r < 16; r++) acc[r] = 0.0f;
        const int mrow = mt * 32 + l31;
        const char* krow = (const char*)Kb + mrow * 256;
        const int sw = (mrow & 15) << 4;
        __builtin_amdgcn_s_setprio(1);
#pragma unroll
        for (int ks = 0; ks < 8; ks++) {
          int cb = (2 * ks + g) << 4;   // bf16 chunk (d>>3), d = 16ks+8g
          bf16x8 kb = *(const bf16x8*)(krow + (cb ^ sw));
          // S^T = K * Q^T : lane holds n=l31, m=(r&3)+8(r>>2)+4g+32mt
          acc = __builtin_amdgcn_mfma_f32_32x32x16_bf16(kb, qf[ks], acc, 0, 0, 0);
        }
        __builtin_amdgcn_s_setprio(0);

        // silu + causal mask, pack bf16 pairs (m, m+1)
        u32 wk[8];
#pragma unroll
        for (int i = 0; i < 8; i++) {
          int r  = 2 * i;
          int mr = m0 + (r & 3) + 8 * (r >> 2) + 4 * g + 32 * mt;
          float p0 = silu_p(acc[r]);
          float p1 = silu_p(acc[r + 1]);
          if (needmask) {
            int nglob = nb + l31;
            if (mr > nglob)     p0 = 0.0f;
            if (mr + 1 > nglob) p1 = 0.0f;
          }
          wk[i] = pkbf(p0, p1);
        }

        // redistribute halves lane<->lane+32 -> PV A-frags (k = 8g + j)
        FragU fa, fb;
        {
          u32 t0 = xor32(wk[0]); u32 t2 = xor32(wk[2]);
          fa.u[0] = g ? t2 : wk[0]; fa.u[2] = g ? wk[2] : t0;
          u32 t1 = xor32(wk[1]); u32 t3 = xor32(wk[3]);
          fa.u[1] = g ? t3 : wk[1]; fa.u[3] = g ? wk[3] : t1;
          u32 t4 = xor32(wk[4]); u32 t6 = xor32(wk[6]);
          fb.u[0] = g ? t6 : wk[4]; fb.u[2] = g ? wk[6] : t4;
          u32 t5 = xor32(wk[5]); u32 t7 = xor32(wk[7]);
          fb.u[1] = g ? t7 : wk[5]; fb.u[3] = g ? wk[7] : t5;
        }
        pa[2 * mt]     = fa.v;
        pa[2 * mt + 1] = fb.v;
      }

      // ---- PV: O += P * V^T (A = P frags in reg, B = V^T from LDS) ----
      __builtin_amdgcn_s_setprio(1);
#pragma unroll
      for (int ks = 0; ks < 4; ks++) {
#pragma unroll
        for (int dt = 0; dt < 4; dt++) {
          int d   = dt * 32 + l31;
          int row = d >> 1;
          int ch  = (d & 1) * 8 + (2 * ks + g);   // m>>3 = 2ks+g
          bf16x8 vb = *(const bf16x8*)((char*)Vtb + row * 256 + ((ch ^ (row & 15)) << 4));
          Of[dt] = __builtin_amdgcn_mfma_f32_32x32x16_bf16(pa[ks], vb, Of[dt], 0, 0, 0);
        }
      }
      __builtin_amdgcn_s_setprio(0);
    }
  }

  // ---- epilogue: coalesced 4B stores for rows n < len ----
#pragma unroll
  for (int dt = 0; dt < 4; dt++) {
    int d = dt * 32 + l31;
#pragma unroll
    for (int r = 0; r < 16; r++) {
      int nloc = 4 * g + (r & 3) + 8 * (r >> 2);
      int n = nb + nloc;
      if (n < len)
        out[(size_t)(off + n) * (HEADS * DQ) + h * DQ + d] = Of[dt][r];
    }
  }
}

extern "C" void kernel_launch(void* const* d_in, const int* in_sizes, int n_in,
                              void* d_out, int out_size, void* d_ws, size_t ws_size,
                              hipStream_t stream) {
  const float* qkv         = (const float*)d_in[0];
  const int*   seq_offsets = (const int*)d_in[1];
  float*       out         = (float*)d_out;
  int Zq = in_sizes[1] - 1;
  dim3 grid(Zq, HEADS);
  hstu_attn_kernel<<<grid, dim3(THREADS), 0, stream>>>(qkv, seq_offsets, out);
}

// Round 4
// 94.387 us; speedup vs baseline: 2.1960x; 1.2539x over previous
//
#include <hip/hip_runtime.h>
#include <hip/hip_bf16.h>

namespace {

constexpr int HEADS = 4;
constexpr int DQ    = 128;
constexpr int KVB   = 64;
constexpr int QB    = 128;
constexpr int NQT   = 3;               // max len 383 -> 3 q-tiles of 128
constexpr int ROWF  = 3 * DQ * HEADS;  // 1536 floats per token row
constexpr float ALPHA = 0.08838834764831843f;
constexpr float INV_N = 1.0f / 512.0f;

typedef __bf16 bf16x8 __attribute__((ext_vector_type(8)));
typedef float  f32x16 __attribute__((ext_vector_type(16)));
typedef float  f32x4  __attribute__((ext_vector_type(4)));
typedef unsigned int u32;
typedef u32 u32x4 __attribute__((ext_vector_type(4)));

union FragU { u32x4 u; bf16x8 v; };

__device__ __forceinline__ u32 pkbf(float lo, float hi) {
  u32 r;
  asm("v_cvt_pk_bf16_f32 %0, %1, %2" : "=v"(r) : "v"(lo), "v"(hi));
  return r;
}

__device__ __forceinline__ u32 xor32(u32 x) {
  return (u32)__shfl_xor((int)x, 32, 64);
}

__device__ __forceinline__ float silu_p(float acc) {
  float s = acc * ALPHA;
  return s * INV_N * __builtin_amdgcn_rcpf(1.0f + __expf(-s));
}

#define GLOAD16(gp, lp) \
  __builtin_amdgcn_global_load_lds((const __attribute__((address_space(1))) u32*)(gp), \
                                   (__attribute__((address_space(3))) u32*)(lp), 16, 0, 0)

} // namespace

// Block = (qt, b, h): 4 waves, wave w owns q-rows qt*128 + 32w .. +31.
// K: f32 double-buffered LDS via global_load_lds (read-time cvt to bf16).
// V: reg-staged (pinned) -> packed bf16 V^T single-buffered LDS.
// Raw barriers keep next-tile loads in flight across phases.
__global__ __launch_bounds__(256, 2)
void hstu_attn_kernel(const float* __restrict__ qkv,
                      const int* __restrict__ seq_offsets,
                      float* __restrict__ out,
                      int Z)
{
  const int xi = blockIdx.x;
  const int qt = (NQT - 1) - xi / Z;          // heavy q-tiles first
  const int b  = (Z - 1) - (xi % Z);          // long sequences first
  const int h  = blockIdx.y;
  const int off = seq_offsets[b];
  const int len = seq_offsets[b + 1] - off;
  if (qt * QB >= len) return;

  __shared__ __align__(16) float          Kf[2][KVB * DQ];  // 2 x 32 KB f32
  __shared__ __align__(16) unsigned short Vtb[KVB * DQ];    // 16 KB bf16 V^T

  const int t   = threadIdx.x;
  const int w   = t >> 6;
  const int l   = t & 63;
  const int l31 = l & 31;
  const int g   = l >> 5;
  const int nb  = qt * QB + 32 * w;   // wave's first q row

  const float* __restrict__ base = qkv + (size_t)off * ROWF + h * (3 * DQ);

  // ---- K staging: 32 gload calls (8/wave), rows 2i,2i+1 per call, 32B-slot swizzle ----
  const int khalf = l >> 5;          // row within pair
  const int kslot = (l & 31) >> 1;   // physical 32B slot 0..15
  const int khb   = l & 1;           // 16B half within slot

  auto issue_k = [&](int m0, int buf) {
#pragma unroll
    for (int j = 0; j < 8; j++) {
      int i  = w * 8 + j;
      int r  = 2 * i + khalf;
      int rm = m0 + r; rm = rm < len ? rm : len - 1;
      int Ls = kslot ^ ((r >> 1) & 15);          // logical 32B slot (involution)
      GLOAD16(base + (size_t)rm * ROWF + DQ + Ls * 8 + khb * 4,
              (char*)Kf[buf] + i * 1024);
    }
  };

  // ---- V staging: thread owns rows (m0p, m0p+1), d-range d0v..d0v+15 ----
  const int m0p = (t >> 3) * 2;
  const int d0v = (t & 7) * 16;
  f32x4 vraw[8];

  auto issue_v = [&](int m0) {
    int r0 = m0 + m0p;     r0 = r0 < len ? r0 : len - 1;
    int r1 = m0 + m0p + 1; r1 = r1 < len ? r1 : len - 1;
    const f32x4* p0 = (const f32x4*)(base + (size_t)r0 * ROWF + 2 * DQ + d0v);
    const f32x4* p1 = (const f32x4*)(base + (size_t)r1 * ROWF + 2 * DQ + d0v);
#pragma unroll
    for (int i = 0; i < 4; i++) { vraw[i] = p0[i]; vraw[4 + i] = p1[i]; }
#pragma unroll
    for (int i = 0; i < 8; i++) asm volatile("" :: "v"(vraw[i]));  // pin: no sinking
  };

  auto pack_v = [&]() {
#pragma unroll
    for (int j = 0; j < 16; j++) {
      int d   = d0v + j;
      int row = d >> 1;
      int ch  = (d & 1) * 8 + (m0p >> 3);
      u32 pv  = pkbf(vraw[j >> 2][j & 3], vraw[4 + (j >> 2)][j & 3]);
      *(u32*)((char*)Vtb + row * 256 + ((ch ^ (row & 15)) << 4) + (m0p & 7) * 2) = pv;
    }
  };

  issue_k(0, 0);
  issue_v(0);

  // ---- Q fragments (B-operand of swapped QK^T): lane holds Q[n=l31][d=16ks+8g+j] ----
  bf16x8 qf[8];
  {
    int n  = nb + l31;
    int rq = n < len ? n : len - 1;   // clamped rows never stored
    const float* qrow = base + (size_t)rq * ROWF;
#pragma unroll
    for (int ks = 0; ks < 8; ks++) {
      int d = ks * 16 + g * 8;
      f32x4 a0 = *(const f32x4*)(qrow + d);
      f32x4 a1 = *(const f32x4*)(qrow + d + 4);
      FragU u;
      u.u[0] = pkbf(a0[0], a0[1]);
      u.u[1] = pkbf(a0[2], a0[3]);
      u.u[2] = pkbf(a1[0], a1[1]);
      u.u[3] = pkbf(a1[2], a1[3]);
      qf[ks] = u.v;
    }
  }

  f32x16 Of[4];
#pragma unroll
  for (int i = 0; i < 4; i++)
#pragma unroll
    for (int r = 0; r < 16; r++) Of[i][r] = 0.0f;

  const int nkv = min((len + KVB - 1) >> 6, 2 * qt + 2);
  int cur = 0;

  for (int kvt = 0; kvt < nkv; kvt++) {
    const int m0 = kvt * KVB;

    pack_v();   // compiler vmcnt wait for vraw drains (older) K gloads too
    if (kvt + 1 < nkv) {
      issue_k(m0 + KVB, cur ^ 1);   // stays in flight across the barrier
      issue_v(m0 + KVB);
    }
    asm volatile("s_waitcnt lgkmcnt(0)" ::: "memory");
    __builtin_amdgcn_s_barrier();
    __builtin_amdgcn_sched_barrier(0);

    if (nb < len && m0 <= nb + 31) {   // wave-uniform causal skip
      const bool needmask = (m0 + KVB - 1) > nb;
      bf16x8 pa[4];

#pragma unroll
      for (int mt = 0; mt < 2; mt++) {
        f32x16 acc;
#pragma unroll
        for (int r = 0; r < 16; r++) acc[r] = 0.0f;
        const int mrow = mt * 32 + l31;
        const char* krow = (const char*)Kf[cur] + mrow * 512;
        const int   ksw  = (mrow >> 1) & 15;
        __builtin_amdgcn_s_setprio(1);
#pragma unroll
        for (int ks = 0; ks < 8; ks++) {
          int J = 2 * ks + g;
          const f32x4* kp = (const f32x4*)(krow + ((J ^ ksw) << 5));
          f32x4 k0 = kp[0], k1 = kp[1];
          FragU u;
          u.u[0] = pkbf(k0[0], k0[1]);
          u.u[1] = pkbf(k0[2], k0[3]);
          u.u[2] = pkbf(k1[0], k1[1]);
          u.u[3] = pkbf(k1[2], k1[3]);
          // S^T = K * Q^T : lane holds n=l31, m=(r&3)+8(r>>2)+4g+32mt
          acc = __builtin_amdgcn_mfma_f32_32x32x16_bf16(u.v, qf[ks], acc, 0, 0, 0);
        }
        __builtin_amdgcn_s_setprio(0);

        // silu + causal mask, pack bf16 pairs (m, m+1)
        u32 wk[8];
#pragma unroll
        for (int i = 0; i < 8; i++) {
          int r  = 2 * i;
          int mr = m0 + (r & 3) + 8 * (r >> 2) + 4 * g + 32 * mt;
          float p0 = silu_p(acc[r]);
          float p1 = silu_p(acc[r + 1]);
          if (needmask) {
            int nglob = nb + l31;
            if (mr > nglob)     p0 = 0.0f;
            if (mr + 1 > nglob) p1 = 0.0f;
          }
          wk[i] = pkbf(p0, p1);
        }

        // redistribute halves lane<->lane+32 -> PV A-frags (k = 8g + j)
        FragU fa, fb;
        {
          u32 t0 = xor32(wk[0]); u32 t2 = xor32(wk[2]);
          fa.u[0] = g ? t2 : wk[0]; fa.u[2] = g ? wk[2] : t0;
          u32 t1 = xor32(wk[1]); u32 t3 = xor32(wk[3]);
          fa.u[1] = g ? t3 : wk[1]; fa.u[3] = g ? wk[3] : t1;
          u32 t4 = xor32(wk[4]); u32 t6 = xor32(wk[6]);
          fb.u[0] = g ? t6 : wk[4]; fb.u[2] = g ? wk[6] : t4;
          u32 t5 = xor32(wk[5]); u32 t7 = xor32(wk[7]);
          fb.u[1] = g ? t7 : wk[5]; fb.u[3] = g ? wk[7] : t5;
        }
        pa[2 * mt]     = fa.v;
        pa[2 * mt + 1] = fb.v;
      }

      // ---- PV: O += P * V^T (A = P frags in reg, B = V^T from LDS) ----
      __builtin_amdgcn_s_setprio(1);
#pragma unroll
      for (int ks = 0; ks < 4; ks++) {
#pragma unroll
        for (int dt = 0; dt < 4; dt++) {
          int d   = dt * 32 + l31;
          int row = d >> 1;
          int ch  = (d & 1) * 8 + (2 * ks + g);   // m>>3 = 2ks+g
          bf16x8 vb = *(const bf16x8*)((char*)Vtb + row * 256 + ((ch ^ (row & 15)) << 4));
          Of[dt] = __builtin_amdgcn_mfma_f32_32x32x16_bf16(pa[ks], vb, Of[dt], 0, 0, 0);
        }
      }
      __builtin_amdgcn_s_setprio(0);
    }

    __builtin_amdgcn_sched_barrier(0);
    __builtin_amdgcn_s_barrier();   // frees Vtb and Kf[cur] for next tile's writes
    cur ^= 1;
  }

  // ---- epilogue: coalesced 4B stores for rows n < len ----
#pragma unroll
  for (int dt = 0; dt < 4; dt++) {
    int d = dt * 32 + l31;
#pragma unroll
    for (int r = 0; r < 16; r++) {
      int nloc = 4 * g + (r & 3) + 8 * (r >> 2);
      int n = nb + nloc;
      if (n < len)
        out[(size_t)(off + n) * (HEADS * DQ) + h * DQ + d] = Of[dt][r];
    }
  }
}

extern "C" void kernel_launch(void* const* d_in, const int* in_sizes, int n_in,
                              void* d_out, int out_size, void* d_ws, size_t ws_size,
                              hipStream_t stream) {
  const float* qkv         = (const float*)d_in[0];
  const int*   seq_offsets = (const int*)d_in[1];
  float*       out         = (float*)d_out;
  int Z = in_sizes[1] - 1;
  dim3 grid(NQT * Z, HEADS);
  hstu_attn_kernel<<<grid, dim3(256), 0, stream>>>(qkv, seq_offsets, out, Z);
}